// Round 6
// baseline (325.688 us; speedup 1.0000x reference)
//
#include <hip/hip_runtime.h>
#include <hip/hip_bf16.h>
#include <hip/hip_cooperative_groups.h>

namespace cg = cooperative_groups;

#define HW 48
#define LNSZ (512 * 48)   // 24576 per sample

typedef __attribute__((ext_vector_type(8))) short bf16x8;  // 8 bf16 (4 VGPRs)
typedef __attribute__((ext_vector_type(4))) float floatx4;

// ---- workspace layout (float offsets) ----
static const size_t WB_OFF  = 0;        // bf16 [1536][512] = 393216 slots
static const size_t BC_OFF  = 393216;   // 512 fp32 biases (theta ++ phi)
static const size_t S_OFF   = 393728;   // 3072 fp32 attention scale (atomic)
static const size_t CXP_OFF = 396800;   // [64][4][48] colsum partials
static const size_t CX2_OFF = 409088;   // [64][4][48] colsumsq partials
static const size_t ST2_OFF = 421376;   // [64][4] float2 ln2 stats
static const size_t XB_OFF  = 421888;   // xb bf16 [64][48][512] = 786432 slots
static const size_t TP_OFF  = 1208320;  // ThPhi bf16 [64][48][512]
static const size_t YB_OFF  = 1994752;  // yb bf16 [64][48][512]
static const size_t UB_OFF  = 2781184;  // ub bf16 [64][48][512]
static const size_t PP_OFF  = 3567616;  // Pp bf16 [768][256] = 98304 slots
static const size_t YY_OFF  = 3665920;  // y fp32 [64][512][48]
static const size_t VV_OFF  = 5238784;  // v fp32 [64][512][48]
// total 6811648 floats = 27.2 MB

// K=512 MFMA micro-GEMM: 2 A-frags (32 o) x 3 B-frags (48 s), prefetched
__device__ __forceinline__ void gemm_k512(
    const __hip_bfloat16* __restrict__ A0, const __hip_bfloat16* __restrict__ A1,
    const __hip_bfloat16* __restrict__ B0, floatx4 acc[2][3]) {
  floatx4 zero = {0.f, 0.f, 0.f, 0.f};
#pragma unroll
  for (int i = 0; i < 2; ++i)
#pragma unroll
    for (int j = 0; j < 3; ++j) acc[i][j] = zero;
  bf16x8 a[2], b[3];
  a[0] = *(const bf16x8*)(A0);
  a[1] = *(const bf16x8*)(A1);
  b[0] = *(const bf16x8*)(B0);
  b[1] = *(const bf16x8*)(B0 + 16 * 512);
  b[2] = *(const bf16x8*)(B0 + 32 * 512);
  for (int k = 0; k < 480; k += 32) {
    bf16x8 an[2], bn[3];
    const int k2 = k + 32;
    an[0] = *(const bf16x8*)(A0 + k2);
    an[1] = *(const bf16x8*)(A1 + k2);
    bn[0] = *(const bf16x8*)(B0 + k2);
    bn[1] = *(const bf16x8*)(B0 + 16 * 512 + k2);
    bn[2] = *(const bf16x8*)(B0 + 32 * 512 + k2);
#pragma unroll
    for (int i = 0; i < 2; ++i)
#pragma unroll
      for (int j = 0; j < 3; ++j)
        acc[i][j] = __builtin_amdgcn_mfma_f32_16x16x32_bf16(a[i], b[j],
                                                            acc[i][j], 0, 0, 0);
    a[0] = an[0]; a[1] = an[1];
    b[0] = bn[0]; b[1] = bn[1]; b[2] = bn[2];
  }
#pragma unroll
  for (int i = 0; i < 2; ++i)
#pragma unroll
    for (int j = 0; j < 3; ++j)
      acc[i][j] = __builtin_amdgcn_mfma_f32_16x16x32_bf16(a[i], b[j],
                                                          acc[i][j], 0, 0, 0);
}

__global__ void __launch_bounds__(256) mega(
    const float* __restrict__ x, const float* __restrict__ tw,
    const float* __restrict__ tb, const float* __restrict__ pw,
    const float* __restrict__ pb, const float* __restrict__ c1w,
    const float* __restrict__ c2w, const float* __restrict__ g1,
    const float* __restrict__ b1, const float* __restrict__ g2,
    const float* __restrict__ b2, float* __restrict__ ws,
    float* __restrict__ out) {
  cg::grid_group grid = cg::this_grid();
  const int t = threadIdx.x;
  const int blk = blockIdx.x;       // 0..255
  const int bx = blk & 3;           // chunk
  const int n = blk >> 2;           // sample
  const int w = t >> 6, lane = t & 63;
  const int c16 = lane & 15, quad = lane >> 4;

  __hip_bfloat16* Wb = (__hip_bfloat16*)(ws + WB_OFF);
  float* bcat        = ws + BC_OFF;
  float* S           = ws + S_OFF;
  float* cxp         = ws + CXP_OFF;
  float* cx2p        = ws + CX2_OFF;
  float2* st2        = (float2*)(ws + ST2_OFF);
  __hip_bfloat16* xb = (__hip_bfloat16*)(ws + XB_OFF);
  __hip_bfloat16* tp = (__hip_bfloat16*)(ws + TP_OFF);
  __hip_bfloat16* yb = (__hip_bfloat16*)(ws + YB_OFF);
  __hip_bfloat16* ub = (__hip_bfloat16*)(ws + UB_OFF);
  __hip_bfloat16* Pp = (__hip_bfloat16*)(ws + PP_OFF);
  float* y           = ws + YY_OFF;
  float* v           = ws + VV_OFF;

  __shared__ float lds[6720];   // 26.9 KB arena shared by all phases

  // ================= P1: pack weights + zero S; x transpose + col stats ====
  {
    for (int g = blk * 256 + t; g < 786432; g += 65536) {
      float vv;
      if (g < 131072)      vv = tw[g];
      else if (g < 262144) vv = pw[g - 131072];
      else if (g < 524288) vv = c1w[g - 262144];
      else                 vv = c2w[g - 524288];
      Wb[g] = __float2bfloat16(vv);
      if (g < 512) bcat[g] = g < 256 ? tb[g] : pb[g - 256];
      if (g < 3072) S[g] = 0.f;
    }
    float* ts = lds;          // 128*49 = 6272
    float* ps = lds + 6272;   // 192
    float* pq = lds + 6464;   // 192
    const float* src = x + (size_t)n * LNSZ + (size_t)bx * 128 * HW;
#pragma unroll
    for (int k = 0; k < 6; ++k) {
      int idx = t + k * 256;               // float4 index over 1536
      float4 vv = ((const float4*)src)[idx];
      int c = idx / 12, sq = (idx % 12) * 4;
      float* d = ts + c * 49 + sq;
      d[0] = vv.x; d[1] = vv.y; d[2] = vv.z; d[3] = vv.w;
    }
    __syncthreads();
    if (t < 192) {
      int s = t % 48, q = t / 48;
      float sum = 0.f, sq2 = 0.f;
#pragma unroll
      for (int c = q * 32; c < q * 32 + 32; ++c) {
        float vv = ts[c * 49 + s];
        sum += vv; sq2 += vv * vv;
      }
      ps[t] = sum; pq[t] = sq2;
    }
    __hip_bfloat16* dst = xb + (size_t)n * LNSZ + bx * 128;
#pragma unroll
    for (int k = 0; k < 12; ++k) {
      int idx = t + k * 256;
      int s = idx >> 6, cp = idx & 63;
      __hip_bfloat162 p;
      p.x = __float2bfloat16(ts[(cp * 2) * 49 + s]);
      p.y = __float2bfloat16(ts[(cp * 2 + 1) * 49 + s]);
      *(__hip_bfloat162*)(dst + (size_t)s * 512 + cp * 2) = p;
    }
    __syncthreads();
    if (t < 48) {
      cxp[((size_t)n * 4 + bx) * 48 + t]  = ps[t] + ps[48 + t] + ps[96 + t] + ps[144 + t];
      cx2p[((size_t)n * 4 + bx) * 48 + t] = pq[t] + pq[48 + t] + pq[96 + t] + pq[144 + t];
    }
  }
  grid.sync();

  // ================= P2: theta+phi proj GEMM -> tp, fused phi max-pool =====
  {
    const int oc = bx;
    const int obase = oc * 128 + w * 32;
    const __hip_bfloat16* A0 = Wb + (size_t)(obase + c16) * 512 + quad * 8;
    const __hip_bfloat16* A1 = A0 + 16 * 512;
    const __hip_bfloat16* B0 = xb + (size_t)n * LNSZ + (size_t)c16 * 512 + quad * 8;
    floatx4 acc[2][3];
    gemm_k512(A0, A1, B0, acc);

    __hip_bfloat16* on = tp + (size_t)n * LNSZ;
    float* tile = lds;  // [128 o_local][49]
#pragma unroll
    for (int i = 0; i < 2; ++i) {
      const int o0 = obase + i * 16 + quad * 4;
      float bv[4];
#pragma unroll
      for (int r = 0; r < 4; ++r) bv[r] = bcat[o0 + r];
#pragma unroll
      for (int j = 0; j < 3; ++j) {
        const int s = j * 16 + c16;
        union { short4 s4; __hip_bfloat16 h[4]; } u;
#pragma unroll
        for (int r = 0; r < 4; ++r) {
          float val = acc[i][j][r] + bv[r];
          u.h[r] = __float2bfloat16(val);
          if (oc >= 2)
            tile[(w * 32 + i * 16 + quad * 4 + r) * 49 + s] = val;
        }
        *(short4*)(on + (size_t)s * 512 + o0) = u.s4;
      }
    }
    if (oc >= 2) {   // phi rows: pool 2x2 -> Pp[(n*12+m)][ (oc-2)*128 + ci ]
      __syncthreads();
      for (int q = t; q < 1536; q += 256) {
        int m = q >> 7, ci = q & 127;
        int sb = (m >> 1) * 8 + (m & 1) * 2;
        const float* tr = tile + ci * 49;
        float mx = fmaxf(fmaxf(tr[sb], tr[sb + 1]), fmaxf(tr[sb + 4], tr[sb + 5]));
        Pp[(size_t)(n * 12 + m) * 256 + (oc - 2) * 128 + ci] = __float2bfloat16(mx);
      }
    }
  }
  grid.sync();

  // ================= P3: score GEMM + pool-max + query-sum -> S ============
  {
    for (int job = blk; job < 384; job += 256) {
      const int bnn = (job & 15) * 48;          // gallery-col block
      const int bmm = (job >> 4) * 128 + w * 32;  // (n,s) row block + wave
      const __hip_bfloat16* A0 = tp + (size_t)(bmm + c16) * 512 + quad * 8;
      const __hip_bfloat16* A1 = A0 + 16 * 512;
      const __hip_bfloat16* Bp = Pp + (size_t)(bnn + c16) * 256 + quad * 8;
      floatx4 zero = {0.f, 0.f, 0.f, 0.f};
      floatx4 acc[2][3];
#pragma unroll
      for (int i = 0; i < 2; ++i)
#pragma unroll
        for (int j = 0; j < 3; ++j) acc[i][j] = zero;
#pragma unroll 2
      for (int k = 0; k < 256; k += 32) {
        bf16x8 a0 = *(const bf16x8*)(A0 + k);
        bf16x8 a1 = *(const bf16x8*)(A1 + k);
        bf16x8 b0 = *(const bf16x8*)(Bp + k);
        bf16x8 b1 = *(const bf16x8*)(Bp + 16 * 256 + k);
        bf16x8 b2 = *(const bf16x8*)(Bp + 32 * 256 + k);
        acc[0][0] = __builtin_amdgcn_mfma_f32_16x16x32_bf16(a0, b0, acc[0][0], 0, 0, 0);
        acc[0][1] = __builtin_amdgcn_mfma_f32_16x16x32_bf16(a0, b1, acc[0][1], 0, 0, 0);
        acc[0][2] = __builtin_amdgcn_mfma_f32_16x16x32_bf16(a0, b2, acc[0][2], 0, 0, 0);
        acc[1][0] = __builtin_amdgcn_mfma_f32_16x16x32_bf16(a1, b0, acc[1][0], 0, 0, 0);
        acc[1][1] = __builtin_amdgcn_mfma_f32_16x16x32_bf16(a1, b1, acc[1][1], 0, 0, 0);
        acc[1][2] = __builtin_amdgcn_mfma_f32_16x16x32_bf16(a1, b2, acc[1][2], 0, 0, 0);
      }
      // per-wave LDS transpose: [col_local*33 + row_local]
      float* rw = lds + w * (48 * 33);
#pragma unroll
      for (int i = 0; i < 2; ++i)
#pragma unroll
        for (int j = 0; j < 3; ++j)
#pragma unroll
          for (int r = 0; r < 4; ++r)
            rw[(j * 16 + c16) * 33 + (i * 16 + quad * 4 + r)] = acc[i][j][r];
      __syncthreads();
      if (lane < 32) {
        float sum = 0.f;
#pragma unroll
        for (int grp = 0; grp < 4; ++grp) {
          float mx = rw[(grp * 12) * 33 + lane];
#pragma unroll
          for (int m = 1; m < 12; ++m)
            mx = fmaxf(mx, rw[(grp * 12 + m) * 33 + lane]);
          sum += mx;
        }
        atomicAdd(&S[bmm + lane], sum * (1.0f / 12.0f));
      }
      __syncthreads();  // protect lds before next job
    }
  }
  grid.sync();

  // ================= P4: LN1 stats (per-block redundant) + norm + transpose
  {
    float* sS   = lds + 6500;  // 48
    float* stat = lds + 6560;  // 2
    if (t < HW) sS[t] = 1.0f + S[n * HW + t];
    if (t < 64) {
      float sum = 0.f, sq = 0.f;
      if (lane < 48) {
        float a = 1.0f + S[n * 48 + lane];
        float cc1 = 0.f, cc2 = 0.f;
#pragma unroll
        for (int ch = 0; ch < 4; ++ch) {
          cc1 += cxp[((size_t)n * 4 + ch) * 48 + lane];
          cc2 += cx2p[((size_t)n * 4 + ch) * 48 + lane];
        }
        sum = a * cc1;
        sq = a * a * cc2;
      }
#pragma unroll
      for (int off = 32; off > 0; off >>= 1) {
        sum += __shfl_down(sum, off, 64);
        sq  += __shfl_down(sq, off, 64);
      }
      if (lane == 0) {
        float mu = sum * (1.0f / LNSZ);
        float var = sq * (1.0f / LNSZ) - mu * mu;
        stat[0] = mu;
        stat[1] = 1.0f / sqrtf(var + 1e-5f);
      }
    }
    __syncthreads();
    const float mu = stat[0], rstd = stat[1];
    float* ts = lds;  // 6272
    const size_t chunk = (size_t)bx * 6144;
    const float* xn = x + (size_t)n * LNSZ + chunk;
    float* yn = y + (size_t)n * LNSZ + chunk;
    const float* gp = g1 + chunk;
    const float* bp = b1 + chunk;
#pragma unroll
    for (int k = 0; k < 6; ++k) {
      int idx = t + k * 256;
      int c = idx / 12, sq0 = (idx % 12) * 4;
      float4 xv = ((const float4*)xn)[idx];
      float4 gv = ((const float4*)gp)[idx];
      float4 bv = ((const float4*)bp)[idx];
      float4 o;
      o.x = (xv.x * sS[sq0]     - mu) * rstd * gv.x + bv.x;
      o.y = (xv.y * sS[sq0 + 1] - mu) * rstd * gv.y + bv.y;
      o.z = (xv.z * sS[sq0 + 2] - mu) * rstd * gv.z + bv.z;
      o.w = (xv.w * sS[sq0 + 3] - mu) * rstd * gv.w + bv.w;
      ((float4*)yn)[idx] = o;
      float* d = ts + c * 49 + sq0;
      d[0] = o.x; d[1] = o.y; d[2] = o.z; d[3] = o.w;
    }
    __syncthreads();
    __hip_bfloat16* dst = yb + (size_t)n * LNSZ + bx * 128;
#pragma unroll
    for (int k = 0; k < 12; ++k) {
      int idx = t + k * 256;
      int s = idx >> 6, cp = idx & 63;
      __hip_bfloat162 p;
      p.x = __float2bfloat16(ts[(cp * 2) * 49 + s]);
      p.y = __float2bfloat16(ts[(cp * 2 + 1) * 49 + s]);
      *(__hip_bfloat162*)(dst + (size_t)s * 512 + cp * 2) = p;
    }
  }
  grid.sync();

  // ================= P5: conv1 + relu -> ub ================================
  {
    const int obase = bx * 128 + w * 32;
    const __hip_bfloat16* A0 = Wb + (size_t)(512 + obase + c16) * 512 + quad * 8;
    const __hip_bfloat16* A1 = A0 + 16 * 512;
    const __hip_bfloat16* B0 = yb + (size_t)n * LNSZ + (size_t)c16 * 512 + quad * 8;
    floatx4 acc[2][3];
    gemm_k512(A0, A1, B0, acc);
    __hip_bfloat16* on = ub + (size_t)n * LNSZ;
#pragma unroll
    for (int i = 0; i < 2; ++i) {
      const int o0 = obase + i * 16 + quad * 4;
#pragma unroll
      for (int j = 0; j < 3; ++j) {
        const int s = j * 16 + c16;
        union { short4 s4; __hip_bfloat16 h[4]; } u;
#pragma unroll
        for (int r = 0; r < 4; ++r)
          u.h[r] = __float2bfloat16(fmaxf(acc[i][j][r], 0.f));
        *(short4*)(on + (size_t)s * 512 + o0) = u.s4;
      }
    }
  }
  grid.sync();

  // ================= P6: conv2 + residual + LN2 stats ======================
  {
    const int obase = bx * 128 + w * 32;
    const __hip_bfloat16* A0 = Wb + (size_t)(1024 + obase + c16) * 512 + quad * 8;
    const __hip_bfloat16* A1 = A0 + 16 * 512;
    const __hip_bfloat16* B0 = ub + (size_t)n * LNSZ + (size_t)c16 * 512 + quad * 8;
    floatx4 acc[2][3];
    gemm_k512(A0, A1, B0, acc);
    const float* yn = y + (size_t)n * LNSZ;
    float* vn = v + (size_t)n * LNSZ;
    float sum = 0.f, sq = 0.f;
#pragma unroll
    for (int i = 0; i < 2; ++i)
#pragma unroll
      for (int r = 0; r < 4; ++r) {
        const int o = obase + i * 16 + quad * 4 + r;
#pragma unroll
        for (int j = 0; j < 3; ++j) {
          const int s = j * 16 + c16;
          float val = acc[i][j][r] + yn[(size_t)o * HW + s];
          vn[(size_t)o * HW + s] = val;
          sum += val;
          sq += val * val;
        }
      }
    // block reduce {sum,sq} via lds scratch
    float* rs = lds;      // 4
    float* rq = lds + 8;  // 4
#pragma unroll
    for (int off = 32; off > 0; off >>= 1) {
      sum += __shfl_down(sum, off, 64);
      sq  += __shfl_down(sq, off, 64);
    }
    if (lane == 0) { rs[w] = sum; rq[w] = sq; }
    __syncthreads();
    if (t == 0)
      st2[n * 4 + bx] = make_float2(rs[0] + rs[1] + rs[2] + rs[3],
                                    rq[0] + rq[1] + rq[2] + rq[3]);
  }
  grid.sync();

  // ================= P7: LN2 norm -> out ===================================
  {
    float* stat = lds + 6560;
    if (t == 0) {
      float s1 = 0.f, s2 = 0.f;
#pragma unroll
      for (int k = 0; k < 4; ++k) {
        float2 p = st2[n * 4 + k];
        s1 += p.x; s2 += p.y;
      }
      float mu = s1 * (1.0f / LNSZ);
      float var = s2 * (1.0f / LNSZ) - mu * mu;
      stat[0] = mu;
      stat[1] = 1.0f / sqrtf(var + 1e-5f);
    }
    __syncthreads();
    const float mu = stat[0], rstd = stat[1];
    const size_t chunk = (size_t)bx * 6144;
    const float* vn = v + (size_t)n * LNSZ + chunk;
    float* on = out + (size_t)n * LNSZ + chunk;
    const float* gp = g2 + chunk;
    const float* bp = b2 + chunk;
#pragma unroll
    for (int k = 0; k < 6; ++k) {
      int idx = t + k * 256;
      float4 vv = ((const float4*)vn)[idx];
      float4 gv = ((const float4*)gp)[idx];
      float4 bv = ((const float4*)bp)[idx];
      float4 o;
      o.x = (vv.x - mu) * rstd * gv.x + bv.x;
      o.y = (vv.y - mu) * rstd * gv.y + bv.y;
      o.z = (vv.z - mu) * rstd * gv.z + bv.z;
      o.w = (vv.w - mu) * rstd * gv.w + bv.w;
      ((float4*)on)[idx] = o;
    }
  }
}

extern "C" void kernel_launch(void* const* d_in, const int* in_sizes, int n_in,
                              void* d_out, int out_size, void* d_ws, size_t ws_size,
                              hipStream_t stream) {
  const float* x   = (const float*)d_in[0];
  const float* tw  = (const float*)d_in[1];
  const float* tb  = (const float*)d_in[2];
  const float* pw  = (const float*)d_in[3];
  const float* pb  = (const float*)d_in[4];
  const float* c1w = (const float*)d_in[5];
  const float* c2w = (const float*)d_in[6];
  const float* g1  = (const float*)d_in[7];
  const float* b1  = (const float*)d_in[8];
  const float* g2  = (const float*)d_in[9];
  const float* b2  = (const float*)d_in[10];
  float* ws  = (float*)d_ws;
  float* outp = (float*)d_out;

  void* args[] = {(void*)&x,  (void*)&tw, (void*)&tb, (void*)&pw, (void*)&pb,
                  (void*)&c1w, (void*)&c2w, (void*)&g1, (void*)&b1,
                  (void*)&g2, (void*)&b2, (void*)&ws, (void*)&outp};
  hipLaunchCooperativeKernel((void*)mega, dim3(256), dim3(256), args, 0, stream);
}

// Round 10
// 141.635 us; speedup vs baseline: 2.2995x; 2.2995x over previous
//
#include <hip/hip_runtime.h>
#include <hip/hip_bf16.h>

#define NN 64
#define CC 512
#define HW 48
#define LNSZ (CC * HW)   // 24576 per sample

typedef __attribute__((ext_vector_type(8))) short bf16x8;  // 8 bf16 (4 VGPRs)
typedef __attribute__((ext_vector_type(4))) float floatx4;

// ---- workspace layout (float offsets) ----
static const size_t WB_OFF   = 0;        // 1536x512 bf16 = 393216 float-slots
static const size_t BC_OFF   = 393216;   // 512 fp32 biases (theta ++ phi)
static const size_t S_OFF    = 393728;   // 3072 fp32 (attention scale, atomic)
static const size_t SMU_OFF  = 396800;   // 64
static const size_t SRS_OFF  = 396864;   // 64
static const size_t CXP_OFF  = 396928;   // [64][4][48] colsum partials
static const size_t CX2_OFF  = 409216;   // [64][4][48] colsumsq partials
static const size_t ST2_OFF  = 421504;   // [64][4] float2 ln2 stats
static const size_t XB_OFF   = 422016;   // [64][48][512] bf16 = 786432 slots
static const size_t TP_OFF   = 1208448;  // ThPhi bf16 [64][48][512]
static const size_t YB_OFF   = 1994880;  // yb bf16 [64][48][512]
static const size_t UB_OFF   = 2781312;  // ub bf16 [64][48][512]
static const size_t PP_OFF   = 3567744;  // Pp bf16 [768][256] = 98304 slots
static const size_t YY_OFF   = 3666048;  // y fp32 [64][512][48]
static const size_t VV_OFF   = 5238912;  // v fp32 [64][512][48]
// total 6811776 floats = 27.2 MB

// block-level {sum, sumsq} reduction; valid result in thread 0
__device__ __forceinline__ void block_reduce2(float& sum, float& sq) {
  const int lane = threadIdx.x & 63, w = threadIdx.x >> 6;
#pragma unroll
  for (int off = 32; off > 0; off >>= 1) {
    sum += __shfl_down(sum, off, 64);
    sq  += __shfl_down(sq, off, 64);
  }
  __shared__ float rs[4], rq[4];
  if (lane == 0) { rs[w] = sum; rq[w] = sq; }
  __syncthreads();
  if (threadIdx.x == 0) {
    sum = rs[0] + rs[1] + rs[2] + rs[3];
    sq  = rq[0] + rq[1] + rq[2] + rq[3];
  }
}

// Pack weights into Wb bf16 [1536][512] (tw 0-255, pw 256-511, c1 512-1023,
// c2 1024-1535), biases into bcat[512], and zero the S accumulator.
__global__ __launch_bounds__(256) void prep_w(
    const float* __restrict__ tw, const float* __restrict__ pw,
    const float* __restrict__ c1, const float* __restrict__ c2,
    const float* __restrict__ tb, const float* __restrict__ pb,
    __hip_bfloat16* __restrict__ Wb, float* __restrict__ bcat,
    float* __restrict__ S) {
  int g = blockIdx.x * 256 + threadIdx.x;  // < 786432
  float v;
  if (g < 131072)      v = tw[g];
  else if (g < 262144) v = pw[g - 131072];
  else if (g < 524288) v = c1[g - 262144];
  else                 v = c2[g - 524288];
  Wb[g] = __float2bfloat16(v);
  if (g < 512) bcat[g] = g < 256 ? tb[g] : pb[g - 256];
  if (g < 3072) S[g] = 0.f;
}

// x fp32 [n][C][48] -> xb bf16 [n][48][512], plus per-(n,chunk,s) column
// sums/sumsq of x (for LN1 stats-for-free).
__global__ __launch_bounds__(256) void trx_stats(
    const float* __restrict__ x, __hip_bfloat16* __restrict__ xb,
    float* __restrict__ cxp, float* __restrict__ cx2p) {
  const int bx = blockIdx.x;   // c-chunk of 128
  const int n  = blockIdx.y;
  const int t  = threadIdx.x;
  __shared__ float ts[128 * 49];
  __shared__ float ps[192], pq[192];
  const float* src = x + (size_t)n * LNSZ + (size_t)bx * 128 * HW;
#pragma unroll
  for (int k = 0; k < 6; ++k) {
    int idx = t + k * 256;               // float4 index over 1536
    float4 v = ((const float4*)src)[idx];
    int c = idx / 12, sq = (idx % 12) * 4;
    float* d = ts + c * 49 + sq;
    d[0] = v.x; d[1] = v.y; d[2] = v.z; d[3] = v.w;
  }
  __syncthreads();
  // column-sum partials: 192 threads, each sums 32 c's for one s
  if (t < 192) {
    int s = t % 48, q = t / 48;
    float sum = 0.f, sq2 = 0.f;
#pragma unroll
    for (int c = q * 32; c < q * 32 + 32; ++c) {
      float v = ts[c * 49 + s];
      sum += v; sq2 += v * v;
    }
    ps[t] = sum; pq[t] = sq2;
  }
  // transposed bf16 writes
  __hip_bfloat16* dst = xb + (size_t)n * LNSZ + bx * 128;
#pragma unroll
  for (int k = 0; k < 12; ++k) {
    int idx = t + k * 256;
    int s = idx >> 6, cp = idx & 63;
    __hip_bfloat162 p;
    p.x = __float2bfloat16(ts[(cp * 2) * 49 + s]);
    p.y = __float2bfloat16(ts[(cp * 2 + 1) * 49 + s]);
    *(__hip_bfloat162*)(dst + (size_t)s * 512 + cp * 2) = p;
  }
  __syncthreads();
  if (t < 48) {
    cxp[((size_t)n * 4 + bx) * 48 + t] = ps[t] + ps[48 + t] + ps[96 + t] + ps[144 + t];
    cx2p[((size_t)n * 4 + bx) * 48 + t] = pq[t] + pq[48 + t] + pq[96 + t] + pq[144 + t];
  }
}

// MFMA GEMM (per-sample), transposed bf16 output:
// outb[n][s][o] = bf16( sum_c Wb[o][c] * inb[n][s][c] + bias[o] ), opt relu.
// Grid (4 o-chunks, 64 n), 256 thr; wave = 32 o x 48 s.
__global__ __launch_bounds__(256) void gemm_bf16out(
    const __hip_bfloat16* __restrict__ Wb, const __hip_bfloat16* __restrict__ inb,
    const float* __restrict__ bias, __hip_bfloat16* __restrict__ outb, int relu) {
  const int oc = blockIdx.x, n = blockIdx.y;
  const int w = threadIdx.x >> 6, lane = threadIdx.x & 63;
  const int c16 = lane & 15, quad = lane >> 4;
  const int obase = oc * 128 + w * 32;

  const __hip_bfloat16* A0 = Wb + (size_t)(obase + c16) * 512 + quad * 8;
  const __hip_bfloat16* A1 = A0 + 16 * 512;
  const __hip_bfloat16* B0 = inb + (size_t)n * LNSZ + (size_t)c16 * 512 + quad * 8;

  floatx4 zero = {0.f, 0.f, 0.f, 0.f};
  floatx4 acc[2][3];
#pragma unroll
  for (int i = 0; i < 2; ++i)
#pragma unroll
    for (int j = 0; j < 3; ++j) acc[i][j] = zero;

  bf16x8 a[2], b[3];
  a[0] = *(const bf16x8*)(A0);
  a[1] = *(const bf16x8*)(A1);
  b[0] = *(const bf16x8*)(B0);
  b[1] = *(const bf16x8*)(B0 + 16 * 512);
  b[2] = *(const bf16x8*)(B0 + 32 * 512);

  for (int k = 0; k < 480; k += 32) {
    bf16x8 an[2], bn[3];
    const int k2 = k + 32;
    an[0] = *(const bf16x8*)(A0 + k2);
    an[1] = *(const bf16x8*)(A1 + k2);
    bn[0] = *(const bf16x8*)(B0 + k2);
    bn[1] = *(const bf16x8*)(B0 + 16 * 512 + k2);
    bn[2] = *(const bf16x8*)(B0 + 32 * 512 + k2);
#pragma unroll
    for (int i = 0; i < 2; ++i)
#pragma unroll
      for (int j = 0; j < 3; ++j)
        acc[i][j] = __builtin_amdgcn_mfma_f32_16x16x32_bf16(a[i], b[j],
                                                            acc[i][j], 0, 0, 0);
    a[0] = an[0]; a[1] = an[1];
    b[0] = bn[0]; b[1] = bn[1]; b[2] = bn[2];
  }
#pragma unroll
  for (int i = 0; i < 2; ++i)
#pragma unroll
    for (int j = 0; j < 3; ++j)
      acc[i][j] = __builtin_amdgcn_mfma_f32_16x16x32_bf16(a[i], b[j],
                                                          acc[i][j], 0, 0, 0);

  __hip_bfloat16* on = outb + (size_t)n * LNSZ;
#pragma unroll
  for (int i = 0; i < 2; ++i) {
    const int o0 = obase + i * 16 + quad * 4;
    float bv[4];
#pragma unroll
    for (int r = 0; r < 4; ++r) bv[r] = bias ? bias[o0 + r] : 0.f;
#pragma unroll
    for (int j = 0; j < 3; ++j) {
      const int s = j * 16 + c16;
      union { short4 s4; __hip_bfloat16 h[4]; } u;
#pragma unroll
      for (int r = 0; r < 4; ++r) {
        float v = acc[i][j][r] + bv[r];
        if (relu) v = fmaxf(v, 0.f);
        u.h[r] = __float2bfloat16(v);
      }
      *(short4*)(on + (size_t)s * 512 + o0) = u.s4;
    }
  }
}

// Pp[(i*12+m)][ci] = max over 2x2 window of ThPhi[i][s][256+ci]
__global__ __launch_bounds__(256) void make_pp(
    const __hip_bfloat16* __restrict__ ThPhi, __hip_bfloat16* __restrict__ Pp) {
  int g = blockIdx.x * 256 + threadIdx.x;  // < 196608
  int ci = g & 255;
  int rest = g >> 8;
  int m = rest % 12, i = rest / 12;
  int sb = (m >> 1) * 8 + (m & 1) * 2;
  const __hip_bfloat16* base = ThPhi + (size_t)i * LNSZ + 256 + ci;
  float mx = __bfloat162float(base[(size_t)(sb + 0) * 512]);
  mx = fmaxf(mx, __bfloat162float(base[(size_t)(sb + 1) * 512]));
  mx = fmaxf(mx, __bfloat162float(base[(size_t)(sb + 4) * 512]));
  mx = fmaxf(mx, __bfloat162float(base[(size_t)(sb + 5) * 512]));
  Pp[g] = __float2bfloat16(mx);
}

// Score GEMM with fused pool-max + query-sum:
// S[row] += (1/12) * sum_{i in block} max_{m<12} (Th[row] . Pp[i*12+m])
// A = ThPhi rows (n,s), stride 512, first 256 cols; B = Pp [768][256].
// Grid (16 col-blocks of 48, 24 row-blocks of 128); wave = 32 rows x 48 cols.
__global__ __launch_bounds__(256) void dgemm_fused(
    const __hip_bfloat16* __restrict__ A, const __hip_bfloat16* __restrict__ B,
    float* __restrict__ S) {
  const int bn = blockIdx.x * 48;
  const int w = threadIdx.x >> 6, lane = threadIdx.x & 63;
  const int c16 = lane & 15, quad = lane >> 4;
  const int bm = blockIdx.y * 128 + w * 32;

  const __hip_bfloat16* A0 = A + (size_t)(bm + c16) * 512 + quad * 8;
  const __hip_bfloat16* A1 = A0 + 16 * 512;
  const __hip_bfloat16* Bp = B + (size_t)(bn + c16) * 256 + quad * 8;

  floatx4 zero = {0.f, 0.f, 0.f, 0.f};
  floatx4 acc[2][3];
#pragma unroll
  for (int i = 0; i < 2; ++i)
#pragma unroll
    for (int j = 0; j < 3; ++j) acc[i][j] = zero;

#pragma unroll 2
  for (int k = 0; k < 256; k += 32) {
    bf16x8 a0 = *(const bf16x8*)(A0 + k);
    bf16x8 a1 = *(const bf16x8*)(A1 + k);
    bf16x8 b0 = *(const bf16x8*)(Bp + k);
    bf16x8 b1 = *(const bf16x8*)(Bp + 16 * 256 + k);
    bf16x8 b2 = *(const bf16x8*)(Bp + 32 * 256 + k);
    acc[0][0] = __builtin_amdgcn_mfma_f32_16x16x32_bf16(a0, b0, acc[0][0], 0, 0, 0);
    acc[0][1] = __builtin_amdgcn_mfma_f32_16x16x32_bf16(a0, b1, acc[0][1], 0, 0, 0);
    acc[0][2] = __builtin_amdgcn_mfma_f32_16x16x32_bf16(a0, b2, acc[0][2], 0, 0, 0);
    acc[1][0] = __builtin_amdgcn_mfma_f32_16x16x32_bf16(a1, b0, acc[1][0], 0, 0, 0);
    acc[1][1] = __builtin_amdgcn_mfma_f32_16x16x32_bf16(a1, b1, acc[1][1], 0, 0, 0);
    acc[1][2] = __builtin_amdgcn_mfma_f32_16x16x32_bf16(a1, b2, acc[1][2], 0, 0, 0);
  }

  // LDS transpose: red[w][col_local*33 + row_local]
  __shared__ float red[4 * 48 * 33];
  float* rw = red + w * (48 * 33);
#pragma unroll
  for (int i = 0; i < 2; ++i)
#pragma unroll
    for (int j = 0; j < 3; ++j)
#pragma unroll
      for (int r = 0; r < 4; ++r)
        rw[(j * 16 + c16) * 33 + (i * 16 + quad * 4 + r)] = acc[i][j][r];
  __syncthreads();
  if (lane < 32) {
    float sum = 0.f;
#pragma unroll
    for (int grp = 0; grp < 4; ++grp) {
      float mx = rw[(grp * 12) * 33 + lane];
#pragma unroll
      for (int m = 1; m < 12; ++m)
        mx = fmaxf(mx, rw[(grp * 12 + m) * 33 + lane]);
      sum += mx;
    }
    atomicAdd(&S[bm + lane], sum * (1.0f / 12.0f));
  }
}

// mu/rstd per sample from colsums + S: one wave per n
__global__ __launch_bounds__(64) void ln1_finish(
    const float* __restrict__ S, const float* __restrict__ cxp,
    const float* __restrict__ cx2p, float* __restrict__ smu,
    float* __restrict__ srstd) {
  const int n = blockIdx.x, lane = threadIdx.x;
  float sum = 0.f, sq = 0.f;
  if (lane < 48) {
    float a = 1.0f + S[n * 48 + lane];
    float c1 = 0.f, c2 = 0.f;
#pragma unroll
    for (int ch = 0; ch < 4; ++ch) {
      c1 += cxp[((size_t)n * 4 + ch) * 48 + lane];
      c2 += cx2p[((size_t)n * 4 + ch) * 48 + lane];
    }
    sum = a * c1;
    sq = a * a * c2;
  }
#pragma unroll
  for (int off = 32; off > 0; off >>= 1) {
    sum += __shfl_down(sum, off, 64);
    sq  += __shfl_down(sq, off, 64);
  }
  if (lane == 0) {
    float mu = sum * (1.0f / LNSZ);
    float var = sq * (1.0f / LNSZ) - mu * mu;
    smu[n] = mu;
    srstd[n] = 1.0f / sqrtf(var + 1e-5f);
  }
}

// y = LN1(x*(1+S)) -> fp32 [c][s] AND bf16 [s][c] (fused transpose)
__global__ __launch_bounds__(256) void ln1_norm_tr(
    const float* __restrict__ x, const float* __restrict__ S,
    const float* __restrict__ smu, const float* __restrict__ srstd,
    const float* __restrict__ g, const float* __restrict__ b,
    float* __restrict__ y, __hip_bfloat16* __restrict__ yb) {
  const int bx = blockIdx.x, n = blockIdx.y, t = threadIdx.x;
  __shared__ float ts[128 * 49];
  __shared__ float sS[HW];
  if (t < HW) sS[t] = 1.0f + S[n * HW + t];
  __syncthreads();
  const float mu = smu[n], rstd = srstd[n];
  const size_t chunk = (size_t)bx * 6144;
  const float* xn = x + (size_t)n * LNSZ + chunk;
  float* yn = y + (size_t)n * LNSZ + chunk;
  const float* gp = g + chunk;
  const float* bp = b + chunk;
#pragma unroll
  for (int k = 0; k < 6; ++k) {
    int idx = t + k * 256;
    int c = idx / 12, sq0 = (idx % 12) * 4;
    float4 xv = ((const float4*)xn)[idx];
    float4 gv = ((const float4*)gp)[idx];
    float4 bv = ((const float4*)bp)[idx];
    float4 o;
    o.x = (xv.x * sS[sq0]     - mu) * rstd * gv.x + bv.x;
    o.y = (xv.y * sS[sq0 + 1] - mu) * rstd * gv.y + bv.y;
    o.z = (xv.z * sS[sq0 + 2] - mu) * rstd * gv.z + bv.z;
    o.w = (xv.w * sS[sq0 + 3] - mu) * rstd * gv.w + bv.w;
    ((float4*)yn)[idx] = o;
    float* d = ts + c * 49 + sq0;
    d[0] = o.x; d[1] = o.y; d[2] = o.z; d[3] = o.w;
  }
  __syncthreads();
  __hip_bfloat16* dst = yb + (size_t)n * LNSZ + bx * 128;
#pragma unroll
  for (int k = 0; k < 12; ++k) {
    int idx = t + k * 256;
    int s = idx >> 6, cp = idx & 63;
    __hip_bfloat162 p;
    p.x = __float2bfloat16(ts[(cp * 2) * 49 + s]);
    p.y = __float2bfloat16(ts[(cp * 2 + 1) * 49 + s]);
    *(__hip_bfloat162*)(dst + (size_t)s * 512 + cp * 2) = p;
  }
}

// conv2 with fused residual + LN2 stats: v = y + Wc2@ub; stats2[n][oc]={S,S2}
__global__ __launch_bounds__(256) void conv2_fused(
    const __hip_bfloat16* __restrict__ Wb, const __hip_bfloat16* __restrict__ inb,
    const float* __restrict__ y, float* __restrict__ v,
    float2* __restrict__ stats2) {
  const int oc = blockIdx.x, n = blockIdx.y;
  const int w = threadIdx.x >> 6, lane = threadIdx.x & 63;
  const int c16 = lane & 15, quad = lane >> 4;
  const int obase = oc * 128 + w * 32;

  const __hip_bfloat16* A0 = Wb + (size_t)(obase + c16) * 512 + quad * 8;
  const __hip_bfloat16* A1 = A0 + 16 * 512;
  const __hip_bfloat16* B0 = inb + (size_t)n * LNSZ + (size_t)c16 * 512 + quad * 8;

  floatx4 zero = {0.f, 0.f, 0.f, 0.f};
  floatx4 acc[2][3];
#pragma unroll
  for (int i = 0; i < 2; ++i)
#pragma unroll
    for (int j = 0; j < 3; ++j) acc[i][j] = zero;

  bf16x8 a[2], b[3];
  a[0] = *(const bf16x8*)(A0);
  a[1] = *(const bf16x8*)(A1);
  b[0] = *(const bf16x8*)(B0);
  b[1] = *(const bf16x8*)(B0 + 16 * 512);
  b[2] = *(const bf16x8*)(B0 + 32 * 512);

  for (int k = 0; k < 480; k += 32) {
    bf16x8 an[2], bn[3];
    const int k2 = k + 32;
    an[0] = *(const bf16x8*)(A0 + k2);
    an[1] = *(const bf16x8*)(A1 + k2);
    bn[0] = *(const bf16x8*)(B0 + k2);
    bn[1] = *(const bf16x8*)(B0 + 16 * 512 + k2);
    bn[2] = *(const bf16x8*)(B0 + 32 * 512 + k2);
#pragma unroll
    for (int i = 0; i < 2; ++i)
#pragma unroll
      for (int j = 0; j < 3; ++j)
        acc[i][j] = __builtin_amdgcn_mfma_f32_16x16x32_bf16(a[i], b[j],
                                                            acc[i][j], 0, 0, 0);
    a[0] = an[0]; a[1] = an[1];
    b[0] = bn[0]; b[1] = bn[1]; b[2] = bn[2];
  }
#pragma unroll
  for (int i = 0; i < 2; ++i)
#pragma unroll
    for (int j = 0; j < 3; ++j)
      acc[i][j] = __builtin_amdgcn_mfma_f32_16x16x32_bf16(a[i], b[j],
                                                          acc[i][j], 0, 0, 0);

  const float* yn = y + (size_t)n * LNSZ;
  float* vn = v + (size_t)n * LNSZ;
  float sum = 0.f, sq = 0.f;
#pragma unroll
  for (int i = 0; i < 2; ++i)
#pragma unroll
    for (int r = 0; r < 4; ++r) {
      const int o = obase + i * 16 + quad * 4 + r;
#pragma unroll
      for (int j = 0; j < 3; ++j) {
        const int s = j * 16 + c16;
        float val = acc[i][j][r] + yn[(size_t)o * HW + s];
        vn[(size_t)o * HW + s] = val;
        sum += val;
        sq += val * val;
      }
    }
  block_reduce2(sum, sq);
  if (threadIdx.x == 0) stats2[n * 4 + oc] = make_float2(sum, sq);
}

__global__ __launch_bounds__(256) void ln2_norm(
    const float* __restrict__ v, const float2* __restrict__ stats2,
    const float* __restrict__ g2, const float* __restrict__ b2,
    float* __restrict__ out) {
  const int bx = blockIdx.x, n = blockIdx.y, t = threadIdx.x;
  __shared__ float smu, srstd;
  if (t == 0) {
    float s1 = 0.f, s2 = 0.f;
#pragma unroll
    for (int k = 0; k < 4; ++k) {
      float2 p = stats2[n * 4 + k];
      s1 += p.x; s2 += p.y;
    }
    float mu = s1 * (1.0f / LNSZ);
    float var = s2 * (1.0f / LNSZ) - mu * mu;
    smu = mu;
    srstd = 1.0f / sqrtf(var + 1e-5f);
  }
  __syncthreads();
  const float mu = smu, rstd = srstd;
  const size_t chunk = (size_t)bx * 6144;
  const float* vn = v + (size_t)n * LNSZ + chunk;
  float* on = out + (size_t)n * LNSZ + chunk;
  const float* gp = g2 + chunk;
  const float* bp = b2 + chunk;
#pragma unroll
  for (int k = 0; k < 6; ++k) {
    int idx = t + k * 256;
    float4 vv = ((const float4*)vn)[idx];
    float4 gv = ((const float4*)gp)[idx];
    float4 bv = ((const float4*)bp)[idx];
    float4 o;
    o.x = (vv.x - mu) * rstd * gv.x + bv.x;
    o.y = (vv.y - mu) * rstd * gv.y + bv.y;
    o.z = (vv.z - mu) * rstd * gv.z + bv.z;
    o.w = (vv.w - mu) * rstd * gv.w + bv.w;
    ((float4*)on)[idx] = o;
  }
}

extern "C" void kernel_launch(void* const* d_in, const int* in_sizes, int n_in,
                              void* d_out, int out_size, void* d_ws, size_t ws_size,
                              hipStream_t stream) {
  const float* x   = (const float*)d_in[0];
  const float* tw  = (const float*)d_in[1];
  const float* tb  = (const float*)d_in[2];
  const float* pw  = (const float*)d_in[3];
  const float* pb  = (const float*)d_in[4];
  const float* c1w = (const float*)d_in[5];
  const float* c2w = (const float*)d_in[6];
  const float* g1  = (const float*)d_in[7];
  const float* b1  = (const float*)d_in[8];
  const float* g2  = (const float*)d_in[9];
  const float* b2  = (const float*)d_in[10];

  float* ws = (float*)d_ws;
  __hip_bfloat16* Wb = (__hip_bfloat16*)(ws + WB_OFF);
  float* bcat        = ws + BC_OFF;
  float* S           = ws + S_OFF;
  float* smu         = ws + SMU_OFF;
  float* srstd       = ws + SRS_OFF;
  float* cxp         = ws + CXP_OFF;
  float* cx2p        = ws + CX2_OFF;
  float2* st2        = (float2*)(ws + ST2_OFF);
  __hip_bfloat16* xb = (__hip_bfloat16*)(ws + XB_OFF);
  __hip_bfloat16* tp = (__hip_bfloat16*)(ws + TP_OFF);
  __hip_bfloat16* yb = (__hip_bfloat16*)(ws + YB_OFF);
  __hip_bfloat16* ub = (__hip_bfloat16*)(ws + UB_OFF);
  __hip_bfloat16* Pp = (__hip_bfloat16*)(ws + PP_OFF);
  float* y           = ws + YY_OFF;
  float* v           = ws + VV_OFF;
  float* out         = (float*)d_out;

  // pack weights/biases, zero S
  prep_w<<<3072, 256, 0, stream>>>(tw, pw, c1w, c2w, tb, pb, Wb, bcat, S);
  // x -> bf16 [s][c] + LN1 column stats
  trx_stats<<<dim3(4, NN), 256, 0, stream>>>(x, xb, cxp, cx2p);
  // theta+phi projection, bias fused, transposed bf16 out (== Th ++ phi)
  gemm_bf16out<<<dim3(4, NN), 256, 0, stream>>>(Wb, xb, bcat, tp, 0);
  make_pp<<<768, 256, 0, stream>>>(tp, Pp);
  // score GEMM + pool-max + query-sum -> S (atomic)
  dgemm_fused<<<dim3(16, 24), 256, 0, stream>>>(tp, Pp, S);
  // LN1 mu/rstd from colsums + S
  ln1_finish<<<NN, 64, 0, stream>>>(S, cxp, cx2p, smu, srstd);
  // LN1 apply -> y fp32 + yb bf16 (fused transpose)
  ln1_norm_tr<<<dim3(4, NN), 256, 0, stream>>>(x, S, smu, srstd, g1, b1, y, yb);
  // conv1 + relu -> ub bf16 [s][c]
  gemm_bf16out<<<dim3(4, NN), 256, 0, stream>>>(Wb + 512 * 512, yb, nullptr, ub, 1);
  // conv2 + residual + LN2 stats
  conv2_fused<<<dim3(4, NN), 256, 0, stream>>>(Wb + 1024 * 512, ub, y, v, st2);
  ln2_norm<<<dim3(4, NN), 256, 0, stream>>>(v, st2, g2, b2, out);
}